// Round 3
// baseline (255.483 us; speedup 1.0000x reference)
//
#include <hip/hip_runtime.h>
#include <stdint.h>

#define B_SZ    16
#define T_LEN   1024
#define C_CH    32
#define TC      (T_LEN * C_CH)      // 32768
#define S_MAIN  128
#define NB_P    400
#define P_TOP   60
#define OUT_CH  (NB_P + P_TOP)      // 460
#define N_MAIN  (S_MAIN * NB_P)     // 51200
#define N_TOP   (T_LEN * P_TOP)     // 61440
#define N_PAIRS (N_MAIN + N_TOP)    // 112640
#define NBLK    2048                // 8 WG/CU exactly; 8192 persistent waves
#define NW      (NBLK * 4)

typedef float        v4f __attribute__((ext_vector_type(4)));
typedef int          v4i __attribute__((ext_vector_type(4)));
typedef unsigned int v4u __attribute__((ext_vector_type(4)));

__device__ __forceinline__ unsigned short f32_to_bf16_rne(float f) {
    unsigned int u = __float_as_uint(f);
    unsigned int r = u + 0x7fffu + ((u >> 16) & 1u);
    return (unsigned short)(r >> 16);
}

__device__ __forceinline__ float leaky(float v) {
    return (v > 0.f) ? v : 0.3f * v;
}

// Gather path: buffer_load_dwordx4, aux=1 (SC0). Measured neutral vs plain
// loads (round 2) but keeps 32-bit voffset addressing; retained unchanged.
#if __has_builtin(__builtin_amdgcn_make_buffer_rsrc) && __has_builtin(__builtin_amdgcn_raw_buffer_load_b128)
  #define RSRC_DECL(ptr) const auto __rsrc = \
      __builtin_amdgcn_make_buffer_rsrc((void*)(ptr), (short)0, TC * 32, 0x00020000)
  #define GATHER16(voff) __builtin_bit_cast(v4u, \
      __builtin_amdgcn_raw_buffer_load_b128(__rsrc, (int)(voff), 0, 1 /*SC0*/))
#else
  #define RSRC_DECL(ptr) const v4u* __rsrc = (ptr)
  #define GATHER16(voff) __rsrc[(unsigned)(voff) >> 4]
#endif

// ---------------------------------------------------------------------------
// Kernel 1: transpose+pack x [B, T*C] f32 -> xb: per index i a 32 B block =
// 16 batches bf16 (half bh = batches 8bh..8bh+7). Total 1 MB -> L2-resident.
// ---------------------------------------------------------------------------
__global__ __launch_bounds__(256) void transpose_pack(const float* __restrict__ x,
                                                      unsigned int* __restrict__ xb) {
    const int i = blockIdx.x * 256 + threadIdx.x;    // [0, TC)
    unsigned int u[8];
    #pragma unroll
    for (int k = 0; k < 8; ++k) {
        float v0 = x[(size_t)(2 * k)     * TC + i];
        float v1 = x[(size_t)(2 * k + 1) * TC + i];
        u[k] = (unsigned int)f32_to_bf16_rne(v0) |
               ((unsigned int)f32_to_bf16_rne(v1) << 16);
    }
    v4u a = { u[0], u[1], u[2], u[3] };
    v4u b = { u[4], u[5], u[6], u[7] };
    v4u* out = (v4u*)xb;
    out[(size_t)i * 2]     = a;   // batches 0..7
    out[(size_t)i * 2 + 1] = b;   // batches 8..15
}

// ---------------------------------------------------------------------------
// Kernel 2: PERSISTENT fused patch compute. 8192 waves grid-stride over
// 112640 pairs (~14 each). Next pair's idx/W prefetched into registers
// during the current pair's gather+reduce -> idx/W HBM latency hidden,
// wave launches cut 14x. Inner math identical to round 0 (bit-exact).
// Epilogue stores are PLAIN (L2-allocate): ws_main/out stay L2-resident
// for the upsample kernel (NT stores in round 2 inflated WRITE 5x).
// ---------------------------------------------------------------------------
__global__ __launch_bounds__(256, 6) void patch_fused(
    const v4u*   __restrict__ xb4,       // [TC*2] 16 B half-blocks
    const int*   __restrict__ idx_main,  // [N_MAIN, 128]
    const float* __restrict__ W_main,    // [N_MAIN, 128]
    const float* __restrict__ bm,        // [N_MAIN]
    const int*   __restrict__ idx_top,   // [N_TOP, 128]
    const float* __restrict__ W_top,     // [N_TOP, 128]
    const float* __restrict__ bt,        // [N_TOP]
    float*       __restrict__ ws_main,   // [16, S_MAIN, NB_P]
    float*       __restrict__ out)       // [16, T, 460]
{
    const int wave = threadIdx.x >> 6;
    const int lane = threadIdx.x & 63;
    const int j    = lane >> 1;       // 0..31: owns indices 4j..4j+3
    const int bh   = lane & 1;        // batch half
    const int bhofs = bh << 4;

    RSRC_DECL(xb4);

    int pair = blockIdx.x * 4 + wave;            // global wave id
    // prologue: load idx/W for the first pair
    {
        // pair < N_PAIRS always (NW=8192 <= N_PAIRS)
    }
    bool m_cur = (pair < N_MAIN);
    int  q_cur = m_cur ? pair : (pair - N_MAIN);
    v4i iv = __builtin_nontemporal_load(
        (const v4i*)((m_cur ? idx_main : idx_top) + (size_t)q_cur * 128) + j);
    v4f wv = __builtin_nontemporal_load(
        (const v4f*)((m_cur ? W_main : W_top) + (size_t)q_cur * 128) + j);

    while (pair < N_PAIRS) {
        // ---- prefetch next pair's idx/W (overlaps gathers+reduce below) ----
        const int pn = pair + NW;
        v4i ivn = iv;
        v4f wvn = wv;
        if (pn < N_PAIRS) {
            const bool mn = (pn < N_MAIN);
            const int  qn = mn ? pn : (pn - N_MAIN);
            ivn = __builtin_nontemporal_load(
                (const v4i*)((mn ? idx_main : idx_top) + (size_t)qn * 128) + j);
            wvn = __builtin_nontemporal_load(
                (const v4f*)((mn ? W_main : W_top) + (size_t)qn * 128) + j);
        }

        // ---- gathers + accumulate for current pair (identical to round 0) ----
        float acc[8];
        #pragma unroll
        for (int k = 0; k < 8; ++k) acc[k] = 0.f;

        const int   ixs[4] = { iv.x, iv.y, iv.z, iv.w };
        const float wts[4] = { wv.x, wv.y, wv.z, wv.w };
        #pragma unroll
        for (int m = 0; m < 4; ++m) {
            const v4u gv = GATHER16((ixs[m] << 5) | bhofs);
            const float wt = wts[m];
            acc[0] += __uint_as_float(gv.x << 16)         * wt;
            acc[1] += __uint_as_float(gv.x & 0xffff0000u) * wt;
            acc[2] += __uint_as_float(gv.y << 16)         * wt;
            acc[3] += __uint_as_float(gv.y & 0xffff0000u) * wt;
            acc[4] += __uint_as_float(gv.z << 16)         * wt;
            acc[5] += __uint_as_float(gv.z & 0xffff0000u) * wt;
            acc[6] += __uint_as_float(gv.w << 16)         * wt;
            acc[7] += __uint_as_float(gv.w & 0xffff0000u) * wt;
        }

        // ---- reduce over j (preserve bh = bit 0): masks 2,4,8,16,32 ----
        #pragma unroll
        for (int m = 2; m <= 32; m <<= 1)
            #pragma unroll
            for (int k = 0; k < 8; ++k)
                acc[k] += __shfl_xor(acc[k], m);

        // ---- epilogue: plain stores (L2-allocate) ----
        if (j == 0) {
            const bool im = (pair < N_MAIN);
            const int  q  = im ? pair : (pair - N_MAIN);
            const float bv = im ? bm[q] : bt[q];
            if (im) {
                const int row = q / NB_P;
                const int p   = q - row * NB_P;
                #pragma unroll
                for (int k = 0; k < 8; ++k) {
                    const int b = bh * 8 + k;
                    ws_main[((size_t)b * S_MAIN + row) * NB_P + p] = leaky(acc[k] + bv);
                }
            } else {
                const int row = q / P_TOP;
                const int p   = q - row * P_TOP;
                #pragma unroll
                for (int k = 0; k < 8; ++k) {
                    const int b = bh * 8 + k;
                    out[((size_t)b * T_LEN + row) * OUT_CH + NB_P + p] = leaky(acc[k] + bv);
                }
            }
        }

        pair = pn;
        iv = ivn;
        wv = wvn;
    }
}

// ---------------------------------------------------------------------------
// Kernel 3: upsample main result x8 along time into the output (coalesced).
// out row = 460 floats = 115 float4; main part = first 100 float4.
// ---------------------------------------------------------------------------
__global__ __launch_bounds__(256) void upsample_main(const float* __restrict__ ws_main,
                                                     float* __restrict__ out) {
    const int o4 = blockIdx.x * 256 + threadIdx.x;   // < B*T*100 = 1,638,400
    const int row = o4 / 100;
    const int col = o4 - row * 100;
    const int b = row >> 10;         // /1024
    const int t = row & 1023;
    const int s = t >> 3;            // /STRETCH
    const v4f v = ((const v4f*)ws_main)[((size_t)b * S_MAIN + s) * 100 + col];
    ((v4f*)out)[(size_t)row * 115 + col] = v;
}

// ---------------------------------------------------------------------------
extern "C" void kernel_launch(void* const* d_in, const int* in_sizes, int n_in,
                              void* d_out, int out_size, void* d_ws, size_t ws_size,
                              hipStream_t stream) {
    const float* x      = (const float*)d_in[0];
    const float* W_main = (const float*)d_in[1];
    const float* b_main = (const float*)d_in[2];
    const float* W_top  = (const float*)d_in[3];
    const float* b_top  = (const float*)d_in[4];
    const int*  idx_main = (const int*)d_in[5];
    const int*  idx_top  = (const int*)d_in[6];
    float* out = (float*)d_out;

    unsigned int* xb   = (unsigned int*)d_ws;                         // 1 MB
    float* ws_main     = (float*)((char*)d_ws + (size_t)TC * 16 * 2); // 3.3 MB

    transpose_pack<<<TC / 256, 256, 0, stream>>>(x, xb);

    patch_fused<<<NBLK, 256, 0, stream>>>(
        (const v4u*)xb, idx_main, W_main, b_main, idx_top, W_top, b_top,
        ws_main, out);

    upsample_main<<<(B_SZ * T_LEN * 100) / 256, 256, 0, stream>>>(ws_main, out);
}

// Round 4
// 240.672 us; speedup vs baseline: 1.0615x; 1.0615x over previous
//
#include <hip/hip_runtime.h>
#include <stdint.h>

#define B_SZ    16
#define T_LEN   1024
#define C_CH    32
#define TC      (T_LEN * C_CH)      // 32768
#define S_MAIN  128
#define NB_P    400
#define P_TOP   60
#define OUT_CH  (NB_P + P_TOP)      // 460
#define N_MAIN  (S_MAIN * NB_P)     // 51200
#define N_TOP   (T_LEN * P_TOP)     // 61440
#define N_PAIRS (N_MAIN + N_TOP)    // 112640

typedef float        v4f __attribute__((ext_vector_type(4)));
typedef int          v4i __attribute__((ext_vector_type(4)));
typedef unsigned int v4u __attribute__((ext_vector_type(4)));

__device__ __forceinline__ unsigned short f32_to_bf16_rne(float f) {
    unsigned int u = __float_as_uint(f);
    unsigned int r = u + 0x7fffu + ((u >> 16) & 1u);
    return (unsigned short)(r >> 16);
}

__device__ __forceinline__ float leaky(float v) {
    return (v > 0.f) ? v : 0.3f * v;
}

// Gather path: buffer_load_dwordx4 aux=1 (SC0). Measured neutral vs plain
// loads (R0 vs R2) -> keep for 32-bit voffset addressing. The gather pipe is
// pinned at ~5 CU-cycles per 64B line across all tested variants (R0/R2/R3):
// layout is transaction-optimal (2x16B adjacent-lane requests merge to the
// minimal 128 line-req/pair), so this is the structural floor.
#if __has_builtin(__builtin_amdgcn_make_buffer_rsrc) && __has_builtin(__builtin_amdgcn_raw_buffer_load_b128)
  #define RSRC_DECL(ptr) const auto __rsrc = \
      __builtin_amdgcn_make_buffer_rsrc((void*)(ptr), (short)0, TC * 32, 0x00020000)
  #define GATHER16(voff) __builtin_bit_cast(v4u, \
      __builtin_amdgcn_raw_buffer_load_b128(__rsrc, (int)(voff), 0, 1 /*SC0*/))
#else
  #define RSRC_DECL(ptr) const v4u* __rsrc = (ptr)
  #define GATHER16(voff) __rsrc[(unsigned)(voff) >> 4]
#endif

// ---------------------------------------------------------------------------
// Kernel 1: transpose+pack x [B, T*C] f32 -> xb: per index i a 32 B block =
// 16 batches bf16 (half bh = batches 8bh..8bh+7). Total 1 MB -> L2-resident.
// ---------------------------------------------------------------------------
__global__ __launch_bounds__(256) void transpose_pack(const float* __restrict__ x,
                                                      unsigned int* __restrict__ xb) {
    const int i = blockIdx.x * 256 + threadIdx.x;    // [0, TC)
    unsigned int u[8];
    #pragma unroll
    for (int k = 0; k < 8; ++k) {
        float v0 = x[(size_t)(2 * k)     * TC + i];
        float v1 = x[(size_t)(2 * k + 1) * TC + i];
        u[k] = (unsigned int)f32_to_bf16_rne(v0) |
               ((unsigned int)f32_to_bf16_rne(v1) << 16);
    }
    v4u a = { u[0], u[1], u[2], u[3] };
    v4u b = { u[4], u[5], u[6], u[7] };
    v4u* out = (v4u*)xb;
    out[(size_t)i * 2]     = a;   // batches 0..7
    out[(size_t)i * 2 + 1] = b;   // batches 8..15
}

// ---------------------------------------------------------------------------
// Kernel 2: fused patch compute (main pairs 0..51199, top pairs 51200..).
// One wave per pair (non-persistent: measured best, R2). lane = j*2+bh:
// j in [0,32) owns 4 indices, bh = batch half (16 B). Gathers via SC0
// buffer loads; idx/W are NT (stream-once, don't displace xb).
// Epilogue stores are PLAIN (L2-allocate): NT stores in R2 inflated
// WRITE_SIZE 5x (partial-line HBM writes) and pushed ws_main out of L2.
// ---------------------------------------------------------------------------
__global__ __launch_bounds__(256) void patch_fused(
    const v4u*   __restrict__ xb4,       // [TC*2] 16 B half-blocks
    const int*   __restrict__ idx_main,  // [N_MAIN, 128]
    const float* __restrict__ W_main,    // [N_MAIN, 128]
    const float* __restrict__ bm,        // [N_MAIN]
    const int*   __restrict__ idx_top,   // [N_TOP, 128]
    const float* __restrict__ W_top,     // [N_TOP, 128]
    const float* __restrict__ bt,        // [N_TOP]
    float*       __restrict__ ws_main,   // [16, S_MAIN, NB_P]
    float*       __restrict__ out)       // [16, T, 460]
{
    const int wave = threadIdx.x >> 6;
    const int lane = threadIdx.x & 63;
    const int pair = blockIdx.x * 4 + wave;
    const int j    = lane >> 1;       // 0..31: owns indices 4j..4j+3
    const int bh   = lane & 1;        // batch half

    const bool is_main = (pair < N_MAIN);
    const int  q       = is_main ? pair : (pair - N_MAIN);
    const int*   idx  = is_main ? idx_main : idx_top;
    const float* W    = is_main ? W_main   : W_top;
    const float* bias = is_main ? bm       : bt;

    RSRC_DECL(xb4);

    const v4i iv = __builtin_nontemporal_load((const v4i*)(idx + (size_t)q * 128) + j);
    const v4f wv = __builtin_nontemporal_load((const v4f*)(W   + (size_t)q * 128) + j);

    float acc[8];
    #pragma unroll
    for (int k = 0; k < 8; ++k) acc[k] = 0.f;

    const int   ixs[4] = { iv.x, iv.y, iv.z, iv.w };
    const float wts[4] = { wv.x, wv.y, wv.z, wv.w };
    const int   bhofs  = bh << 4;
    #pragma unroll
    for (int m = 0; m < 4; ++m) {
        const v4u gv = GATHER16((ixs[m] << 5) | bhofs);   // SC0: L2-direct
        const float wt = wts[m];
        acc[0] += __uint_as_float(gv.x << 16)         * wt;
        acc[1] += __uint_as_float(gv.x & 0xffff0000u) * wt;
        acc[2] += __uint_as_float(gv.y << 16)         * wt;
        acc[3] += __uint_as_float(gv.y & 0xffff0000u) * wt;
        acc[4] += __uint_as_float(gv.z << 16)         * wt;
        acc[5] += __uint_as_float(gv.z & 0xffff0000u) * wt;
        acc[6] += __uint_as_float(gv.w << 16)         * wt;
        acc[7] += __uint_as_float(gv.w & 0xffff0000u) * wt;
    }

    // Reduce over j (preserve bh = bit 0): masks 2,4,8,16,32.
    #pragma unroll
    for (int m = 2; m <= 32; m <<= 1)
        #pragma unroll
        for (int k = 0; k < 8; ++k)
            acc[k] += __shfl_xor(acc[k], m);

    if (j == 0) {                     // lanes 0 (batches 0-7), 1 (batches 8-15)
        const float bv = bias[q];
        if (is_main) {
            const int row = q / NB_P;
            const int p   = q - row * NB_P;
            #pragma unroll
            for (int k = 0; k < 8; ++k) {
                const int b = bh * 8 + k;
                ws_main[((size_t)b * S_MAIN + row) * NB_P + p] = leaky(acc[k] + bv);
            }
        } else {
            const int row = q / P_TOP;
            const int p   = q - row * P_TOP;
            #pragma unroll
            for (int k = 0; k < 8; ++k) {
                const int b = bh * 8 + k;
                out[((size_t)b * T_LEN + row) * OUT_CH + NB_P + p] = leaky(acc[k] + bv);
            }
        }
    }
}

// ---------------------------------------------------------------------------
// Kernel 3: upsample main result x8 along time into the output (coalesced).
// out row = 460 floats = 115 float4; main part = first 100 float4.
// ---------------------------------------------------------------------------
__global__ __launch_bounds__(256) void upsample_main(const float* __restrict__ ws_main,
                                                     float* __restrict__ out) {
    const int o4 = blockIdx.x * 256 + threadIdx.x;   // < B*T*100 = 1,638,400
    const int row = o4 / 100;
    const int col = o4 - row * 100;
    const int b = row >> 10;         // /1024
    const int t = row & 1023;
    const int s = t >> 3;            // /STRETCH
    const v4f v = ((const v4f*)ws_main)[((size_t)b * S_MAIN + s) * 100 + col];
    ((v4f*)out)[(size_t)row * 115 + col] = v;
}

// ---------------------------------------------------------------------------
extern "C" void kernel_launch(void* const* d_in, const int* in_sizes, int n_in,
                              void* d_out, int out_size, void* d_ws, size_t ws_size,
                              hipStream_t stream) {
    const float* x      = (const float*)d_in[0];
    const float* W_main = (const float*)d_in[1];
    const float* b_main = (const float*)d_in[2];
    const float* W_top  = (const float*)d_in[3];
    const float* b_top  = (const float*)d_in[4];
    const int*  idx_main = (const int*)d_in[5];
    const int*  idx_top  = (const int*)d_in[6];
    float* out = (float*)d_out;

    unsigned int* xb   = (unsigned int*)d_ws;                         // 1 MB
    float* ws_main     = (float*)((char*)d_ws + (size_t)TC * 16 * 2); // 3.3 MB

    transpose_pack<<<TC / 256, 256, 0, stream>>>(x, xb);

    patch_fused<<<N_PAIRS / 4, 256, 0, stream>>>(
        (const v4u*)xb, idx_main, W_main, b_main, idx_top, W_top, b_top,
        ws_main, out);

    upsample_main<<<(B_SZ * T_LEN * 100) / 256, 256, 0, stream>>>(ws_main, out);
}